// Round 8
// baseline (155.721 us; speedup 1.0000x reference)
//
#include <hip/hip_runtime.h>
#include <math.h>

typedef __attribute__((ext_vector_type(8))) short short8;
typedef __attribute__((ext_vector_type(4))) float f32x4;

namespace {
constexpr int BATCH = 4096;
constexpr int SEQT  = 256;
constexpr int INSZ  = 24;
constexpr int H     = 40;
constexpr int NOUT  = 24;
constexpr int R     = 16;    // batch rows per block, grid = 256 (1 block/CU)
constexpr int NT    = 512;   // 8 waves (2/SIMD): 0-5 gate pairs, 6-7 FC pair

__device__ __forceinline__ unsigned short f2bf(float f) {
  unsigned int u = __float_as_uint(f);
  return (unsigned short)((u + 0x7FFFu + ((u >> 16) & 1u)) >> 16);  // RNE
}
__device__ __forceinline__ float4 ld4(const float* p) {
  return *reinterpret_cast<const float4*>(p);
}
// Native-rate transcendentals (v_exp_f32/v_rcp_f32, ~1 ulp) — avoids the IEEE
// div sequence the compiler emits without fast-math (R7: -22% VALUBusy).
__device__ __forceinline__ float sigm(float v) {
  return __builtin_amdgcn_rcpf(1.0f + __builtin_amdgcn_exp2f(v * -1.442695041f));
}
__device__ __forceinline__ float tanh_fast(float v) {
  return fmaf(2.0f,
              __builtin_amdgcn_rcpf(1.0f + __builtin_amdgcn_exp2f(v * -2.885390082f)),
              -1.0f);
}
}  // namespace

// Raw barrier: drain only LDS ops; global prefetches/stores stay in flight.
#define BAR()                                              \
  asm volatile("s_waitcnt lgkmcnt(0)" ::: "memory");       \
  __builtin_amdgcn_s_barrier();                            \
  __builtin_amdgcn_sched_barrier(0);

// 8-wave pair-split: waves 2g,2g+1 both compute gate tile g (u=g*16+lm) with
// IDENTICAL 8 MFMAs (matrix pipe ~6% busy -> duplication free), then each wave
// does activations for 2 of the 4 D-rows (ih = (w&1)*2). Total transcendental
// work per CU unchanged, per-wave chain halves, 2 waves/SIMD hide the stalls
// that dominated R7 (1810 cyc/step at ~400 cyc of issue).
__global__ __launch_bounds__(NT) void gru_mfma8(
    const float* __restrict__ x, const float* __restrict__ Wih,
    const float* __restrict__ Whh, const float* __restrict__ bih,
    const float* __restrict__ bhh, const float* __restrict__ Wfc,
    const float* __restrict__ bfc, float* __restrict__ out,
    float* __restrict__ hid) {
  __shared__ __align__(16) unsigned short Abuf[2 * 1024];

  const int tid = threadIdx.x;
  const int l   = tid & 63;
  const int w   = tid >> 6;
  const int lm  = l & 15;
  const int lq  = l >> 4;
  const int gb0 = blockIdx.x * R;

  if (tid < 256) reinterpret_cast<uint4*>(Abuf)[tid] = make_uint4(0, 0, 0, 0);

  const int aBase0 = ((lm * 64 + lq * 8)      ^ ((lm & 7) << 3));
  const int aBase1 = ((lm * 64 + lq * 8 + 32) ^ ((lm & 7) << 3));

  // ---------------- gate role (waves 0..5, pair per tile) ----------------
  short8 B[4][2];
  float bias[4] = {0, 0, 0, 0};
  float hold[2] = {0, 0};
  int aw[2] = {0, 0};
  int u = 0, ih = 0;
  bool gvalid = false;
  if (w < 6) {
    const int g = w >> 1;          // tile 0..2
    ih = (w & 1) * 2;              // row-half: i in {ih, ih+1}
    u = g * 16 + lm;
    gvalid = (u < H);
#pragma unroll
    for (int z = 0; z < 4; ++z) {
#pragma unroll
      for (int kt = 0; kt < 2; ++kt) {
        short8 b;
#pragma unroll
        for (int j = 0; j < 8; ++j) {
          const int k = kt * 32 + lq * 8 + j;
          float v = 0.0f;
          if (gvalid) {
            if (z == 0)      v = (k < 24) ? Wih[u * 24 + k]          : Whh[u * 40 + (k - 24)];
            else if (z == 1) v = (k < 24) ? Wih[(40 + u) * 24 + k]   : Whh[(40 + u) * 40 + (k - 24)];
            else if (z == 2) v = (k < 24) ? Wih[(80 + u) * 24 + k]   : 0.0f;
            else             v = (k < 24) ? 0.0f                     : Whh[(80 + u) * 40 + (k - 24)];
          }
          b[j] = (short)f2bf(v);
        }
        B[z][kt] = b;
      }
    }
    if (gvalid) {
      bias[0] = bih[u] + bhh[u];
      bias[1] = bih[40 + u] + bhh[40 + u];
      bias[2] = bih[80 + u];           // n input bias
      bias[3] = bhh[80 + u];           // n hidden bias (scaled by r)
    }
#pragma unroll
    for (int j = 0; j < 2; ++j) {
      const int row = lq * 4 + ih + j;
      aw[j] = ((row * 64 + 24 + u) ^ ((row & 7) << 3));
    }
  }

  // ---------------- FC + x role (waves 6,7, pair-split by rows) ----------------
  short8 F[2][2];
  float biasF[2] = {0, 0};
  float* orow2[2] = {nullptr, nullptr};
  int fw = 0;
  const float* xp = nullptr;
  int xw = 0;
  bool xvalid = false;
  float4 xA = make_float4(0, 0, 0, 0), xB = make_float4(0, 0, 0, 0);
  if (w >= 6) {
    fw = w - 6;                      // 0: rows {0,1}, 1: rows {2,3} of each lq-quad
#pragma unroll
    for (int f = 0; f < 2; ++f) {
      const int o = f * 16 + lm;
#pragma unroll
      for (int kt = 0; kt < 2; ++kt) {
        short8 b;
#pragma unroll
        for (int j = 0; j < 8; ++j) {
          const int k = kt * 32 + lq * 8 + j;
          const float v = (o < NOUT && k >= 24) ? Wfc[o * H + (k - 24)] : 0.0f;
          b[j] = (short)f2bf(v);
        }
        F[f][kt] = b;
      }
      biasF[f] = (o < NOUT) ? bfc[o] : 0.0f;
    }
#pragma unroll
    for (int j = 0; j < 2; ++j)
      orow2[j] = out + ((size_t)(gb0 + lq * 4 + fw * 2 + j) * SEQT) * NOUT;

    // x staging: 96 float4 items (16 rows x 6); wave6 items 0..63, wave7 64..95
    const int item = (fw == 0) ? l : 64 + l;
    xvalid = (fw == 0) || (l < 32);
    const int xr = item / 6, xc = (item - xr * 6) * 4;
    if (xvalid) xp = x + ((size_t)(gb0 + xr) * SEQT) * INSZ + xc;
    xw = ((xr * 64 + xc) ^ ((xr & 7) << 3));
  }

  __syncthreads();  // Abuf zeroed

  if (w >= 6 && xvalid) {  // stage x(0) into buf0; prefetch x(1), x(2)
    const float4 v0 = ld4(xp);
    *reinterpret_cast<uint2*>(&Abuf[xw]) = make_uint2(
        (unsigned)f2bf(v0.x) | ((unsigned)f2bf(v0.y) << 16),
        (unsigned)f2bf(v0.z) | ((unsigned)f2bf(v0.w) << 16));
    xA = ld4(xp + 1 * INSZ);
    xB = ld4(xp + 2 * INSZ);
  }
  __syncthreads();  // x(0) staged

#define GATE_STEP(BO, NBO)                                                      \
  if (w < 6) {                                                                  \
    const short8 A0 = *reinterpret_cast<const short8*>(&Abuf[(BO) + aBase0]);   \
    const short8 A1 = *reinterpret_cast<const short8*>(&Abuf[(BO) + aBase1]);   \
    f32x4 ar = {bias[0], bias[0], bias[0], bias[0]};                            \
    f32x4 az = {bias[1], bias[1], bias[1], bias[1]};                            \
    f32x4 ax = {bias[2], bias[2], bias[2], bias[2]};                            \
    f32x4 ah = {bias[3], bias[3], bias[3], bias[3]};                            \
    ar = __builtin_amdgcn_mfma_f32_16x16x32_bf16(A0, B[0][0], ar, 0, 0, 0);     \
    az = __builtin_amdgcn_mfma_f32_16x16x32_bf16(A0, B[1][0], az, 0, 0, 0);     \
    ax = __builtin_amdgcn_mfma_f32_16x16x32_bf16(A0, B[2][0], ax, 0, 0, 0);     \
    ah = __builtin_amdgcn_mfma_f32_16x16x32_bf16(A0, B[3][0], ah, 0, 0, 0);     \
    ar = __builtin_amdgcn_mfma_f32_16x16x32_bf16(A1, B[0][1], ar, 0, 0, 0);     \
    az = __builtin_amdgcn_mfma_f32_16x16x32_bf16(A1, B[1][1], az, 0, 0, 0);     \
    ax = __builtin_amdgcn_mfma_f32_16x16x32_bf16(A1, B[2][1], ax, 0, 0, 0);     \
    ah = __builtin_amdgcn_mfma_f32_16x16x32_bf16(A1, B[3][1], ah, 0, 0, 0);     \
    _Pragma("unroll")                                                           \
    for (int j = 0; j < 2; ++j) {                                               \
      const float arv = ih ? ar[2 + j] : ar[j];                                 \
      const float azv = ih ? az[2 + j] : az[j];                                 \
      const float axv = ih ? ax[2 + j] : ax[j];                                 \
      const float ahv = ih ? ah[2 + j] : ah[j];                                 \
      const float rr = sigm(arv);                                               \
      const float zz = sigm(azv);                                               \
      const float nn = tanh_fast(fmaf(rr, ahv, axv));                           \
      const float h  = fmaf(zz, hold[j] - nn, nn);                              \
      hold[j] = h;                                                              \
      if (gvalid) Abuf[(NBO) + aw[j]] = f2bf(h);                                \
    }                                                                           \
  }

#define XSTAGE(T, NBO, XS)                                                      \
  if (w >= 6 && xvalid) {                                                       \
    *reinterpret_cast<uint2*>(&Abuf[(NBO) + xw]) = make_uint2(                  \
        (unsigned)f2bf(XS.x) | ((unsigned)f2bf(XS.y) << 16),                    \
        (unsigned)f2bf(XS.z) | ((unsigned)f2bf(XS.w) << 16));                   \
    if ((T) + 3 < SEQT) XS = ld4(xp + (size_t)((T) + 3) * INSZ);                \
  }

#define FC_STEP(T, NBO)                                                         \
  if (w >= 6) {                                                                 \
    const short8 hA0 = *reinterpret_cast<const short8*>(&Abuf[(NBO) + aBase0]); \
    const short8 hA1 = *reinterpret_cast<const short8*>(&Abuf[(NBO) + aBase1]); \
    f32x4 f0 = {biasF[0], biasF[0], biasF[0], biasF[0]};                        \
    f32x4 f1 = {biasF[1], biasF[1], biasF[1], biasF[1]};                        \
    f0 = __builtin_amdgcn_mfma_f32_16x16x32_bf16(hA0, F[0][0], f0, 0, 0, 0);    \
    f1 = __builtin_amdgcn_mfma_f32_16x16x32_bf16(hA0, F[1][0], f1, 0, 0, 0);    \
    f0 = __builtin_amdgcn_mfma_f32_16x16x32_bf16(hA1, F[0][1], f0, 0, 0, 0);    \
    f1 = __builtin_amdgcn_mfma_f32_16x16x32_bf16(hA1, F[1][1], f1, 0, 0, 0);    \
    _Pragma("unroll")                                                           \
    for (int j = 0; j < 2; ++j) {                                               \
      const float v0 = fw ? f0[2 + j] : f0[j];                                  \
      const float v1 = fw ? f1[2 + j] : f1[j];                                  \
      orow2[j][(size_t)(T) * NOUT + lm] = sigm(v0);                             \
      if (lm < 8) orow2[j][(size_t)(T) * NOUT + 16 + lm] = sigm(v1);            \
    }                                                                           \
  }

  for (int tt = 0; tt < SEQT; tt += 2) {
    // step t = tt (even): cur buf 0, next buf 1
    GATE_STEP(0, 1024)
    XSTAGE(tt, 1024, xA)
    BAR()
    FC_STEP(tt, 1024)
    // step t = tt+1 (odd): cur buf 1, next buf 0
    GATE_STEP(1024, 0)
    XSTAGE(tt + 1, 0, xB)
    BAR()
    FC_STEP(tt + 1, 0)
  }

  // final hidden state from registers (each gate wave: its 2 rows)
  if (w < 6 && gvalid) {
#pragma unroll
    for (int j = 0; j < 2; ++j)
      hid[(size_t)(gb0 + lq * 4 + ih + j) * H + u] = hold[j];
  }
}

extern "C" void kernel_launch(void* const* d_in, const int* in_sizes, int n_in,
                              void* d_out, int out_size, void* d_ws, size_t ws_size,
                              hipStream_t stream) {
  const float* x   = (const float*)d_in[0];
  const float* Wih = (const float*)d_in[1];
  const float* Whh = (const float*)d_in[2];
  const float* bih = (const float*)d_in[3];
  const float* bhh = (const float*)d_in[4];
  const float* Wfc = (const float*)d_in[5];
  const float* bfc = (const float*)d_in[6];
  float* out = (float*)d_out;
  float* hid = out + (size_t)BATCH * SEQT * NOUT;

  dim3 grid(BATCH / R);
  dim3 block(NT);
  hipLaunchKernelGGL(gru_mfma8, grid, block, 0, stream,
                     x, Wih, Whh, bih, bhh, Wfc, bfc, out, hid);
}